// Round 1
// baseline (976.398 us; speedup 1.0000x reference)
//
#include <hip/hip_runtime.h>
#include <hip/hip_bf16.h>
#include <stdint.h>

#define B_   4
#define S_   2048
#define D_   1024
#define F_   4096
#define E_   8
#define KSEL 512

typedef __attribute__((ext_vector_type(8))) short short8;
typedef __attribute__((ext_vector_type(4))) float floatx4;

__device__ __forceinline__ unsigned short f2bf(float f) {
    unsigned u = __float_as_uint(f);
    unsigned r = (u + 0x7FFFu + ((u >> 16) & 1u)) >> 16;   // RNE
    return (unsigned short)r;
}

__device__ __forceinline__ void gload16(const void* g, void* l) {
    __builtin_amdgcn_global_load_lds(
        (const __attribute__((address_space(1))) void*)g,
        (__attribute__((address_space(3))) void*)l, 16, 0, 0);
}

// ---------------------------------------------------------------- converts
__global__ void convert_kernel(const float* __restrict__ src,
                               unsigned short* __restrict__ dst, int n4) {
    int i = blockIdx.x * blockDim.x + threadIdx.x;
    int stride = gridDim.x * blockDim.x;
    const float4* s4 = (const float4*)src;
    ushort4* d4 = (ushort4*)dst;
    for (; i < n4; i += stride) {
        float4 v = s4[i];
        ushort4 o;
        o.x = f2bf(v.x); o.y = f2bf(v.y); o.z = f2bf(v.z); o.w = f2bf(v.w);
        d4[i] = o;
    }
}

// ---------------------------------------------------------------- router
// one block (256 thr) per token: logits over 8 experts + softmax
__global__ void router_kernel(const float* __restrict__ x,
                              const float* __restrict__ choice,
                              float* __restrict__ probs) {
    int bs = blockIdx.x;               // 0..8191
    int b = bs >> 11, s = bs & 2047;
    int tid = threadIdx.x;
    const float4* xr = (const float4*)(x + (size_t)bs * D_);
    float4 xv = xr[tid];
    float acc[E_];
#pragma unroll
    for (int e = 0; e < E_; e++) {
        const float4* cr = (const float4*)(choice + e * D_);
        float4 cv = cr[tid];
        acc[e] = xv.x * cv.x + xv.y * cv.y + xv.z * cv.z + xv.w * cv.w;
    }
    __shared__ float red[E_][4];
    int lane = tid & 63, w = tid >> 6;
#pragma unroll
    for (int e = 0; e < E_; e++) {
        float v = acc[e];
        for (int off = 32; off; off >>= 1) v += __shfl_down(v, off, 64);
        if (lane == 0) red[e][w] = v;
    }
    __syncthreads();
    if (tid == 0) {
        float l[E_], m = -1e30f;
#pragma unroll
        for (int e = 0; e < E_; e++) {
            l[e] = red[e][0] + red[e][1] + red[e][2] + red[e][3];
            m = fmaxf(m, l[e]);
        }
        float sum = 0.f, p[E_];
#pragma unroll
        for (int e = 0; e < E_; e++) { p[e] = __expf(l[e] - m); sum += p[e]; }
        float inv = 1.0f / sum;
#pragma unroll
        for (int e = 0; e < E_; e++)
            probs[((size_t)b * E_ + e) * S_ + s] = p[e] * inv;
    }
}

// ---------------------------------------------------------------- top-k by rank
// rank under (prob desc, idx asc) is a permutation; rank<512 -> slot=rank.
__global__ void topk_kernel(const float* __restrict__ probs,
                            int* __restrict__ idxb, float* __restrict__ gateb) {
    __shared__ float ps[S_];
    int be = blockIdx.x >> 3;          // 0..31  (b*8+e)
    int chunk = blockIdx.x & 7;
    const float* p = probs + (size_t)be * S_;
    for (int i = threadIdx.x; i < S_; i += 256) ps[i] = p[i];
    __syncthreads();
    int t = chunk * 256 + threadIdx.x;
    float pt = ps[t];
    int rank = 0;
    for (int s = 0; s < S_; s++) {
        float v = ps[s];
        rank += (v > pt) || (v == pt && s < t);
    }
    if (rank < KSEL) {
        idxb[be * KSEL + rank] = t;
        gateb[be * KSEL + rank] = pt;
    }
}

// ---------------------------------------------------------------- GEMM1 + SiLU
// C[512,4096] = gather(xb)[512,1024] @ w1[e][4096,1024]^T ; h = silu(C) bf16
__global__ __launch_bounds__(256) void gemm1_silu(
    const unsigned short* __restrict__ xb, const unsigned short* __restrict__ w1b,
    const int* __restrict__ idxb, unsigned short* __restrict__ hbuf) {
    __shared__ alignas(16) unsigned short As[128 * 32];
    __shared__ alignas(16) unsigned short Bs[128 * 32];
    const int tid = threadIdx.x;
    const int g = blockIdx.y;          // b*8+e
    const int b = g >> 3, e = g & 7;
    const int tile_m = blockIdx.x & 3;
    const int tile_n = blockIdx.x >> 2;   // 0..31

    const int r0 = tid >> 2, r1 = r0 + 64;
    const int colb = (tid & 3) * 16;   // byte offset in 64B row-chunk
    const int t0 = idxb[g * KSEL + tile_m * 128 + r0];
    const int t1 = idxb[g * KSEL + tile_m * 128 + r1];
    const char* ga0 = (const char*)(xb + ((size_t)b * S_ + t0) * D_) + colb;
    const char* ga1 = (const char*)(xb + ((size_t)b * S_ + t1) * D_) + colb;
    const char* gb0 = (const char*)(w1b + ((size_t)e * F_ + tile_n * 128 + r0) * D_) + colb;
    const char* gb1 = (const char*)(w1b + ((size_t)e * F_ + tile_n * 128 + r1) * D_) + colb;
    char* lA0 = (char*)As + tid * 16; char* lA1 = lA0 + 4096;
    char* lB0 = (char*)Bs + tid * 16; char* lB1 = lB0 + 4096;

    const int lane = tid & 63;
    const int wm = (tid >> 6) >> 1, wn = (tid >> 6) & 1;
    const int mrow = lane & 15;
    const int koff = (lane >> 4) * 8;

    floatx4 acc[4][4];
#pragma unroll
    for (int i = 0; i < 4; i++) {
#pragma unroll
        for (int j = 0; j < 4; j++) acc[i][j] = (floatx4){0.f, 0.f, 0.f, 0.f};
    }

    for (int kt = 0; kt < D_; kt += 32) {
        const int kb = kt * 2;
        gload16(ga0 + kb, lA0); gload16(ga1 + kb, lA1);
        gload16(gb0 + kb, lB0); gload16(gb1 + kb, lB1);
        __syncthreads();
        short8 af[4], bfr[4];
#pragma unroll
        for (int i = 0; i < 4; i++)
            af[i] = *(const short8*)(As + (wm * 64 + i * 16 + mrow) * 32 + koff);
#pragma unroll
        for (int j = 0; j < 4; j++)
            bfr[j] = *(const short8*)(Bs + (wn * 64 + j * 16 + mrow) * 32 + koff);
#pragma unroll
        for (int i = 0; i < 4; i++) {
#pragma unroll
            for (int j = 0; j < 4; j++)
                acc[i][j] = __builtin_amdgcn_mfma_f32_16x16x32_bf16(af[i], bfr[j], acc[i][j], 0, 0, 0);
        }
        __syncthreads();
    }

    unsigned short* hr = hbuf + (size_t)g * (KSEL * F_);
#pragma unroll
    for (int i = 0; i < 4; i++) {
#pragma unroll
        for (int r = 0; r < 4; r++) {
            int rowc = tile_m * 128 + wm * 64 + i * 16 + (lane >> 4) * 4 + r;
#pragma unroll
            for (int j = 0; j < 4; j++) {
                int colc = tile_n * 128 + wn * 64 + j * 16 + mrow;
                float v = acc[i][j][r];
                float s = v / (1.0f + __expf(-v));
                hr[(size_t)rowc * F_ + colc] = f2bf(s);
            }
        }
    }
}

// ---------------------------------------------------------------- GEMM2 + gate*scatter
// C[512,1024] = h[512,4096] @ w2[e][1024,4096]^T ; out[b, idx, :] += gate*C
__global__ __launch_bounds__(256) void gemm2_scatter(
    const unsigned short* __restrict__ hbuf, const unsigned short* __restrict__ w2b,
    const int* __restrict__ idxb, const float* __restrict__ gateb,
    float* __restrict__ out) {
    __shared__ alignas(16) unsigned short As[128 * 32];
    __shared__ alignas(16) unsigned short Bs[128 * 32];
    const int tid = threadIdx.x;
    const int g = blockIdx.y;
    const int b = g >> 3, e = g & 7;
    const int tile_m = blockIdx.x & 3;
    const int tile_n = blockIdx.x >> 2;   // 0..7

    const int r0 = tid >> 2, r1 = r0 + 64;
    const int colb = (tid & 3) * 16;
    const char* ga0 = (const char*)(hbuf + ((size_t)g * KSEL + tile_m * 128 + r0) * F_) + colb;
    const char* ga1 = (const char*)(hbuf + ((size_t)g * KSEL + tile_m * 128 + r1) * F_) + colb;
    const char* gb0 = (const char*)(w2b + ((size_t)e * D_ + tile_n * 128 + r0) * F_) + colb;
    const char* gb1 = (const char*)(w2b + ((size_t)e * D_ + tile_n * 128 + r1) * F_) + colb;
    char* lA0 = (char*)As + tid * 16; char* lA1 = lA0 + 4096;
    char* lB0 = (char*)Bs + tid * 16; char* lB1 = lB0 + 4096;

    const int lane = tid & 63;
    const int wm = (tid >> 6) >> 1, wn = (tid >> 6) & 1;
    const int mrow = lane & 15;
    const int koff = (lane >> 4) * 8;

    floatx4 acc[4][4];
#pragma unroll
    for (int i = 0; i < 4; i++) {
#pragma unroll
        for (int j = 0; j < 4; j++) acc[i][j] = (floatx4){0.f, 0.f, 0.f, 0.f};
    }

    for (int kt = 0; kt < F_; kt += 32) {
        const int kb = kt * 2;
        gload16(ga0 + kb, lA0); gload16(ga1 + kb, lA1);
        gload16(gb0 + kb, lB0); gload16(gb1 + kb, lB1);
        __syncthreads();
        short8 af[4], bfr[4];
#pragma unroll
        for (int i = 0; i < 4; i++)
            af[i] = *(const short8*)(As + (wm * 64 + i * 16 + mrow) * 32 + koff);
#pragma unroll
        for (int j = 0; j < 4; j++)
            bfr[j] = *(const short8*)(Bs + (wn * 64 + j * 16 + mrow) * 32 + koff);
#pragma unroll
        for (int i = 0; i < 4; i++) {
#pragma unroll
            for (int j = 0; j < 4; j++)
                acc[i][j] = __builtin_amdgcn_mfma_f32_16x16x32_bf16(af[i], bfr[j], acc[i][j], 0, 0, 0);
        }
        __syncthreads();
    }

#pragma unroll
    for (int i = 0; i < 4; i++) {
#pragma unroll
        for (int r = 0; r < 4; r++) {
            int rslot = tile_m * 128 + wm * 64 + i * 16 + (lane >> 4) * 4 + r;
            int t = idxb[g * KSEL + rslot];
            float gt = gateb[g * KSEL + rslot];
            float* orow = out + ((size_t)b * S_ + t) * D_;
#pragma unroll
            for (int j = 0; j < 4; j++) {
                int colc = tile_n * 128 + wn * 64 + j * 16 + mrow;
                atomicAdd(&orow[colc], gt * acc[i][j][r]);
            }
        }
    }
}

// ---------------------------------------------------------------- launch
extern "C" void kernel_launch(void* const* d_in, const int* in_sizes, int n_in,
                              void* d_out, int out_size, void* d_ws, size_t ws_size,
                              hipStream_t stream) {
    const float* x      = (const float*)d_in[0];
    const float* choice = (const float*)d_in[1];
    const float* w1     = (const float*)d_in[2];
    const float* w2     = (const float*)d_in[3];
    float* out = (float*)d_out;
    char* ws = (char*)d_ws;

    // workspace layout (bytes)
    unsigned short* w1b = (unsigned short*)(ws);                  // 67,108,864
    unsigned short* w2b = (unsigned short*)(ws + 67108864);       // 67,108,864
    unsigned short* xb  = (unsigned short*)(ws + 134217728);      // 16,777,216
    unsigned short* hb  = (unsigned short*)(ws + 150994944);      // 134,217,728
    float* probs        = (float*)(ws + 285212672);               // 262,144
    int*   idxb         = (int*)(ws + 285474816);                 // 65,536
    float* gateb        = (float*)(ws + 285540352);               // 65,536

    hipMemsetAsync(d_out, 0, (size_t)out_size * sizeof(float), stream);
    convert_kernel<<<8192, 256, 0, stream>>>(w1, w1b, 8388608);
    convert_kernel<<<8192, 256, 0, stream>>>(w2, w2b, 8388608);
    convert_kernel<<<2048, 256, 0, stream>>>(x, xb, 2097152);
    router_kernel<<<B_ * S_, 256, 0, stream>>>(x, choice, probs);
    topk_kernel<<<B_ * E_ * 8, 256, 0, stream>>>(probs, idxb, gateb);
    gemm1_silu<<<dim3(128, 32), 256, 0, stream>>>(xb, w1b, idxb, hb);
    gemm2_scatter<<<dim3(32, 32), 256, 0, stream>>>(hb, w2b, idxb, gateb, out);
}

// Round 2
// 818.929 us; speedup vs baseline: 1.1923x; 1.1923x over previous
//
#include <hip/hip_runtime.h>
#include <hip/hip_bf16.h>
#include <stdint.h>

#define B_   4
#define S_   2048
#define D_   1024
#define F_   4096
#define E_   8
#define KSEL 512

typedef __attribute__((ext_vector_type(8))) short short8;
typedef __attribute__((ext_vector_type(4))) float floatx4;

__device__ __forceinline__ unsigned short f2bf(float f) {
    unsigned u = __float_as_uint(f);
    unsigned r = (u + 0x7FFFu + ((u >> 16) & 1u)) >> 16;   // RNE
    return (unsigned short)r;
}

__device__ __forceinline__ void gload16(const void* g, void* l) {
    __builtin_amdgcn_global_load_lds(
        (const __attribute__((address_space(1))) void*)g,
        (__attribute__((address_space(3))) void*)l, 16, 0, 0);
}

// ---------------------------------------------------------------- converts
__global__ void convert_kernel(const float* __restrict__ src,
                               unsigned short* __restrict__ dst, int n4) {
    int i = blockIdx.x * blockDim.x + threadIdx.x;
    int stride = gridDim.x * blockDim.x;
    const float4* s4 = (const float4*)src;
    ushort4* d4 = (ushort4*)dst;
    for (; i < n4; i += stride) {
        float4 v = s4[i];
        ushort4 o;
        o.x = f2bf(v.x); o.y = f2bf(v.y); o.z = f2bf(v.z); o.w = f2bf(v.w);
        d4[i] = o;
    }
}

// ---------------------------------------------------------------- router (+ x->bf16 fused)
// one block (256 thr) per token: logits over 8 experts + softmax; also emit xb
__global__ void router_kernel(const float* __restrict__ x,
                              const float* __restrict__ choice,
                              float* __restrict__ probs,
                              unsigned short* __restrict__ xb) {
    int bs = blockIdx.x;               // 0..8191
    int b = bs >> 11, s = bs & 2047;
    int tid = threadIdx.x;
    const float4* xr = (const float4*)(x + (size_t)bs * D_);
    float4 xv = xr[tid];
    // fused x -> bf16 convert (coalesced ushort4 per thread)
    ushort4 o;
    o.x = f2bf(xv.x); o.y = f2bf(xv.y); o.z = f2bf(xv.z); o.w = f2bf(xv.w);
    ((ushort4*)(xb + (size_t)bs * D_))[tid] = o;

    float acc[E_];
#pragma unroll
    for (int e = 0; e < E_; e++) {
        const float4* cr = (const float4*)(choice + e * D_);
        float4 cv = cr[tid];
        acc[e] = xv.x * cv.x + xv.y * cv.y + xv.z * cv.z + xv.w * cv.w;
    }
    __shared__ float red[E_][4];
    int lane = tid & 63, w = tid >> 6;
#pragma unroll
    for (int e = 0; e < E_; e++) {
        float v = acc[e];
        for (int off = 32; off; off >>= 1) v += __shfl_down(v, off, 64);
        if (lane == 0) red[e][w] = v;
    }
    __syncthreads();
    if (tid == 0) {
        float l[E_], m = -1e30f;
#pragma unroll
        for (int e = 0; e < E_; e++) {
            l[e] = red[e][0] + red[e][1] + red[e][2] + red[e][3];
            m = fmaxf(m, l[e]);
        }
        float sum = 0.f, p[E_];
#pragma unroll
        for (int e = 0; e < E_; e++) { p[e] = __expf(l[e] - m); sum += p[e]; }
        float inv = 1.0f / sum;
#pragma unroll
        for (int e = 0; e < E_; e++)
            probs[((size_t)b * E_ + e) * S_ + s] = p[e] * inv;
    }
}

// ---------------------------------------------------------------- top-k by rank
// rank under (prob desc, idx asc) is a permutation; rank<512 -> slot=rank.
__global__ void topk_kernel(const float* __restrict__ probs,
                            int* __restrict__ idxb, float* __restrict__ gateb) {
    __shared__ float ps[S_];
    int be = blockIdx.x >> 3;          // 0..31  (b*8+e)
    int chunk = blockIdx.x & 7;
    const float* p = probs + (size_t)be * S_;
    for (int i = threadIdx.x; i < S_; i += 256) ps[i] = p[i];
    __syncthreads();
    int t = chunk * 256 + threadIdx.x;
    float pt = ps[t];
    int rank = 0;
    for (int s = 0; s < S_; s++) {
        float v = ps[s];
        rank += (v > pt) || (v == pt && s < t);
    }
    if (rank < KSEL) {
        idxb[be * KSEL + rank] = t;
        gateb[be * KSEL + rank] = pt;
    }
}

// ---------------------------------------------------------------- GEMM1 + SiLU
// C[512,4096] = gather(xb)[512,1024] @ w1[e][4096,1024]^T ; h = silu(C) bf16
// flat grid 4096, XCD-swizzled: e = blk & 7 (one expert per XCD for L2 reuse)
__global__ __launch_bounds__(256) void gemm1_silu(
    const unsigned short* __restrict__ xb, const unsigned short* __restrict__ w1b,
    const int* __restrict__ idxb, unsigned short* __restrict__ hbuf) {
    __shared__ alignas(16) unsigned short As[128 * 32];
    __shared__ alignas(16) unsigned short Bs[128 * 32];
    const int tid = threadIdx.x;
    const int blk = blockIdx.x;            // 0..4095
    const int e = blk & 7;                 // XCD id (heuristic: rr dispatch)
    const int i = blk >> 3;                // 0..511
    const int b = i >> 7;                  // 0..3
    const int r = i & 127;
    const int tile_n = r >> 2;             // 0..31 (adjacent 4 blocks share B tile)
    const int tile_m = r & 3;
    const int g = b * 8 + e;

    const int r0 = tid >> 2, r1 = r0 + 64;
    const int colb = (tid & 3) * 16;   // byte offset in 64B row-chunk
    const int t0 = idxb[g * KSEL + tile_m * 128 + r0];
    const int t1 = idxb[g * KSEL + tile_m * 128 + r1];
    const char* ga0 = (const char*)(xb + ((size_t)b * S_ + t0) * D_) + colb;
    const char* ga1 = (const char*)(xb + ((size_t)b * S_ + t1) * D_) + colb;
    const char* gb0 = (const char*)(w1b + ((size_t)e * F_ + tile_n * 128 + r0) * D_) + colb;
    const char* gb1 = (const char*)(w1b + ((size_t)e * F_ + tile_n * 128 + r1) * D_) + colb;
    char* lA0 = (char*)As + tid * 16; char* lA1 = lA0 + 4096;
    char* lB0 = (char*)Bs + tid * 16; char* lB1 = lB0 + 4096;

    const int lane = tid & 63;
    const int wm = (tid >> 6) >> 1, wn = (tid >> 6) & 1;
    const int mrow = lane & 15;
    const int koff = (lane >> 4) * 8;

    floatx4 acc[4][4];
#pragma unroll
    for (int i2 = 0; i2 < 4; i2++) {
#pragma unroll
        for (int j = 0; j < 4; j++) acc[i2][j] = (floatx4){0.f, 0.f, 0.f, 0.f};
    }

    for (int kt = 0; kt < D_; kt += 32) {
        const int kb = kt * 2;
        gload16(ga0 + kb, lA0); gload16(ga1 + kb, lA1);
        gload16(gb0 + kb, lB0); gload16(gb1 + kb, lB1);
        __syncthreads();
        short8 af[4], bfr[4];
#pragma unroll
        for (int i2 = 0; i2 < 4; i2++)
            af[i2] = *(const short8*)(As + (wm * 64 + i2 * 16 + mrow) * 32 + koff);
#pragma unroll
        for (int j = 0; j < 4; j++)
            bfr[j] = *(const short8*)(Bs + (wn * 64 + j * 16 + mrow) * 32 + koff);
#pragma unroll
        for (int i2 = 0; i2 < 4; i2++) {
#pragma unroll
            for (int j = 0; j < 4; j++)
                acc[i2][j] = __builtin_amdgcn_mfma_f32_16x16x32_bf16(af[i2], bfr[j], acc[i2][j], 0, 0, 0);
        }
        __syncthreads();
    }

    unsigned short* hr = hbuf + (size_t)g * (KSEL * F_);
#pragma unroll
    for (int i2 = 0; i2 < 4; i2++) {
#pragma unroll
        for (int r2 = 0; r2 < 4; r2++) {
            int rowc = tile_m * 128 + wm * 64 + i2 * 16 + (lane >> 4) * 4 + r2;
#pragma unroll
            for (int j = 0; j < 4; j++) {
                int colc = tile_n * 128 + wn * 64 + j * 16 + mrow;
                float v = acc[i2][j][r2];
                float s = v / (1.0f + __expf(-v));
                hr[(size_t)rowc * F_ + colc] = f2bf(s);
            }
        }
    }
}

// ---------------------------------------------------------------- GEMM2 + gate*scatter
// C[512,1024] = h[512,4096] @ w2[e][1024,4096]^T ; out[b, idx, :] += gate*C
// flat grid 2048 (split-K=2), XCD-swizzled: e = blk & 7
__global__ __launch_bounds__(256) void gemm2_scatter(
    const unsigned short* __restrict__ hbuf, const unsigned short* __restrict__ w2b,
    const int* __restrict__ idxb, const float* __restrict__ gateb,
    float* __restrict__ out) {
    __shared__ alignas(16) unsigned short As[128 * 32];
    __shared__ alignas(16) unsigned short Bs[128 * 32];
    const int tid = threadIdx.x;
    const int blk = blockIdx.x;            // 0..2047
    const int e = blk & 7;                 // XCD id
    const int i = blk >> 3;                // 0..255
    const int b = i >> 6;                  // 0..3
    const int t = i & 63;
    const int tile_n = t >> 3;             // 0..7
    const int kspl = (t >> 2) & 1;         // split-K half
    const int tile_m = t & 3;
    const int g = b * 8 + e;

    const int r0 = tid >> 2, r1 = r0 + 64;
    const int colb = (tid & 3) * 16;
    const char* ga0 = (const char*)(hbuf + ((size_t)g * KSEL + tile_m * 128 + r0) * F_) + colb;
    const char* ga1 = (const char*)(hbuf + ((size_t)g * KSEL + tile_m * 128 + r1) * F_) + colb;
    const char* gb0 = (const char*)(w2b + ((size_t)e * D_ + tile_n * 128 + r0) * F_) + colb;
    const char* gb1 = (const char*)(w2b + ((size_t)e * D_ + tile_n * 128 + r1) * F_) + colb;
    char* lA0 = (char*)As + tid * 16; char* lA1 = lA0 + 4096;
    char* lB0 = (char*)Bs + tid * 16; char* lB1 = lB0 + 4096;

    const int lane = tid & 63;
    const int wm = (tid >> 6) >> 1, wn = (tid >> 6) & 1;
    const int mrow = lane & 15;
    const int koff = (lane >> 4) * 8;

    floatx4 acc[4][4];
#pragma unroll
    for (int i2 = 0; i2 < 4; i2++) {
#pragma unroll
        for (int j = 0; j < 4; j++) acc[i2][j] = (floatx4){0.f, 0.f, 0.f, 0.f};
    }

    const int k0 = kspl * (F_ / 2);
    for (int kt = k0; kt < k0 + F_ / 2; kt += 32) {
        const int kb = kt * 2;
        gload16(ga0 + kb, lA0); gload16(ga1 + kb, lA1);
        gload16(gb0 + kb, lB0); gload16(gb1 + kb, lB1);
        __syncthreads();
        short8 af[4], bfr[4];
#pragma unroll
        for (int i2 = 0; i2 < 4; i2++)
            af[i2] = *(const short8*)(As + (wm * 64 + i2 * 16 + mrow) * 32 + koff);
#pragma unroll
        for (int j = 0; j < 4; j++)
            bfr[j] = *(const short8*)(Bs + (wn * 64 + j * 16 + mrow) * 32 + koff);
#pragma unroll
        for (int i2 = 0; i2 < 4; i2++) {
#pragma unroll
            for (int j = 0; j < 4; j++)
                acc[i2][j] = __builtin_amdgcn_mfma_f32_16x16x32_bf16(af[i2], bfr[j], acc[i2][j], 0, 0, 0);
        }
        __syncthreads();
    }

#pragma unroll
    for (int i2 = 0; i2 < 4; i2++) {
#pragma unroll
        for (int r2 = 0; r2 < 4; r2++) {
            int rslot = tile_m * 128 + wm * 64 + i2 * 16 + (lane >> 4) * 4 + r2;
            int tok = idxb[g * KSEL + rslot];
            float gt = gateb[g * KSEL + rslot];
            float* orow = out + ((size_t)b * S_ + tok) * D_;
#pragma unroll
            for (int j = 0; j < 4; j++) {
                int colc = tile_n * 128 + wn * 64 + j * 16 + mrow;
                atomicAdd(&orow[colc], gt * acc[i2][j][r2]);
            }
        }
    }
}

// ---------------------------------------------------------------- launch
extern "C" void kernel_launch(void* const* d_in, const int* in_sizes, int n_in,
                              void* d_out, int out_size, void* d_ws, size_t ws_size,
                              hipStream_t stream) {
    const float* x      = (const float*)d_in[0];
    const float* choice = (const float*)d_in[1];
    const float* w1     = (const float*)d_in[2];
    const float* w2     = (const float*)d_in[3];
    float* out = (float*)d_out;
    char* ws = (char*)d_ws;

    // workspace layout (bytes)
    unsigned short* w1b = (unsigned short*)(ws);                  // 67,108,864
    unsigned short* w2b = (unsigned short*)(ws + 67108864);       // 67,108,864
    unsigned short* xb  = (unsigned short*)(ws + 134217728);      // 16,777,216
    unsigned short* hb  = (unsigned short*)(ws + 150994944);      // 134,217,728
    float* probs        = (float*)(ws + 285212672);               // 262,144
    int*   idxb         = (int*)(ws + 285474816);                 // 65,536
    float* gateb        = (float*)(ws + 285540352);               // 65,536

    hipMemsetAsync(d_out, 0, (size_t)out_size * sizeof(float), stream);
    convert_kernel<<<8192, 256, 0, stream>>>(w1, w1b, 8388608);
    convert_kernel<<<8192, 256, 0, stream>>>(w2, w2b, 8388608);
    router_kernel<<<B_ * S_, 256, 0, stream>>>(x, choice, probs, xb);
    topk_kernel<<<B_ * E_ * 8, 256, 0, stream>>>(probs, idxb, gateb);
    gemm1_silu<<<4096, 256, 0, stream>>>(xb, w1b, idxb, hb);
    gemm2_scatter<<<2048, 256, 0, stream>>>(hb, w2b, idxb, gateb, out);
}